// Round 9
// baseline (520.542 us; speedup 1.0000x reference)
//
#include <hip/hip_runtime.h>
#include <hip/hip_bf16.h>
#include <math.h>

#define BB 8
#define LL 2500
#define LPAD 2560
#define DD 100
#define FF 50
#define FP 64
#define YY 8000
#define KS 9
#define LCH 256
#define NCH 10

typedef __attribute__((ext_vector_type(8))) short short8;
typedef __attribute__((ext_vector_type(4))) float f32x4;
typedef float f32x4u __attribute__((ext_vector_type(4), aligned(4)));

__device__ inline f32x4 mfma_bf16(short8 a, short8 b, f32x4 c) {
    return __builtin_amdgcn_mfma_f32_16x16x32_bf16(a, b, c, 0, 0, 0);
}

__device__ inline unsigned short f2bf(float x) {
    unsigned int u = __builtin_bit_cast(unsigned int, x);
    unsigned int r = u + 0x7fffu + ((u >> 16) & 1u);
    return (unsigned short)(r >> 16);
}

__device__ inline unsigned long long pack4bf(const float* a) {
    return (unsigned long long)f2bf(a[0])
         | ((unsigned long long)f2bf(a[1]) << 16)
         | ((unsigned long long)f2bf(a[2]) << 32)
         | ((unsigned long long)f2bf(a[3]) << 48);
}

__device__ inline float bf2f(unsigned short s) {
    return __builtin_bit_cast(float, (unsigned int)s << 16);
}

__device__ inline float tanhfast(float x) {
    float e = __expf(2.f * x);
    return 1.f - 2.f / (e + 1.f);
}

// ---- prep: weights -> wA[64][9][128] bf16; U_w -> Ub[Y][64] bf16 ----
__global__ void k_prep(const float* __restrict__ cw, unsigned short* __restrict__ wA,
                       const float* __restrict__ Uw, unsigned short* __restrict__ Ub) {
    int i = blockIdx.x * blockDim.x + threadIdx.x;
    if (i < 64 * KS * 128) {
        int f = i / (KS * 128);
        int r = i - f * (KS * 128);
        int kk = r >> 7;
        int d = r & 127;
        float v = (f < FF && d < DD) ? cw[(f * DD + d) * KS + kk] : 0.f;
        wA[i] = f2bf(v);
    }
    if (i < YY * FP) {
        int y = i >> 6, f = i & 63;
        float v = (f < FF) ? Uw[y * FF + f] : 0.f;
        Ub[i] = f2bf(v);
    }
}

// ---- kernel A: embed + conv1d(MFMA) + tanh -> hB[b][2560][64], hT[b][64][2560] bf16 ----
__global__ __launch_bounds__(256) void k_conv(const int* __restrict__ x,
                                              const float* __restrict__ embW,
                                              const unsigned short* __restrict__ wA,
                                              const float* __restrict__ cb,
                                              unsigned short* __restrict__ hB,
                                              unsigned short* __restrict__ hT) {
    __shared__ unsigned short eL[72 * 136];
    __shared__ int sX[72];
    int b = blockIdx.x & 7;
    int t = blockIdx.x >> 3;
    int l0 = t * 64;
    int tid = threadIdx.x;

    if (tid < 72) {
        int gl = l0 - 4 + tid;
        sX[tid] = (gl >= 0 && gl < LL) ? x[b * LL + gl] : -1;
    }
    __syncthreads();
    for (int i = tid; i < 72 * 25; i += 256) {
        int row = i / 25, c = i - row * 25;
        int id = sX[row];
        float4 v = make_float4(0.f, 0.f, 0.f, 0.f);
        if (id >= 0) v = *(const float4*)(embW + (size_t)id * DD + c * 4);
        float a[4] = {v.x, v.y, v.z, v.w};
        *(unsigned long long*)&eL[row * 136 + c * 4] = pack4bf(a);
    }
    for (int i = tid; i < 72 * 9; i += 256) {
        int row = i / 9, c = i - row * 9;
        *(unsigned long long*)&eL[row * 136 + 100 + c * 4] = 0ull;
    }
    __syncthreads();

    int w = tid >> 6, lane = tid & 63, lm = lane & 15, g = lane >> 4;
    f32x4 cacc[4];
#pragma unroll
    for (int mt = 0; mt < 4; ++mt) cacc[mt] = (f32x4){0.f, 0.f, 0.f, 0.f};

    for (int kk = 0; kk < KS; ++kk) {
#pragma unroll
        for (int dc = 0; dc < 4; ++dc) {
            short8 bfrag = *(const short8*)&eL[(w * 16 + lm + kk) * 136 + dc * 32 + g * 8];
#pragma unroll
            for (int mt = 0; mt < 4; ++mt) {
                short8 afrag = *(const short8*)(wA + ((mt * 16 + lm) * KS + kk) * 128 + dc * 32 + g * 8);
                cacc[mt] = mfma_bf16(afrag, bfrag, cacc[mt]);
            }
        }
    }

    int l = l0 + w * 16 + lm;
    unsigned long long packs[4];
#pragma unroll
    for (int mt = 0; mt < 4; ++mt) {
        float vals[4];
#pragma unroll
        for (int j = 0; j < 4; ++j) {
            int f = mt * 16 + g * 4 + j;
            vals[j] = (f < FF) ? tanhfast(cacc[mt][j] + cb[f]) : 0.f;
        }
        packs[mt] = pack4bf(vals);
        *(unsigned long long*)&hB[((size_t)b * LPAD + l) * FP + mt * 16 + g * 4] = packs[mt];
    }
    __syncthreads();
    unsigned short* hTile = eL;
#pragma unroll
    for (int mt = 0; mt < 4; ++mt)
#pragma unroll
        for (int j = 0; j < 4; ++j)
            hTile[(mt * 16 + g * 4 + j) * 72 + w * 16 + lm] =
                (unsigned short)(packs[mt] >> (16 * j));
    __syncthreads();
    {
        int f = tid >> 2, q = tid & 3;
        short8 v0 = *(const short8*)&hTile[f * 72 + q * 16];
        short8 v1 = *(const short8*)&hTile[f * 72 + q * 16 + 8];
        unsigned short* dst = hT + ((size_t)b * FP + f) * LPAD + l0 + q * 16;
        *(short8*)dst = v0;
        *(short8*)(dst + 8) = v1;
    }
}

// ---- kernel B: fused attention; block = (b, 32 y); 256-l chunks; wave-per-row dump ----
__global__ __launch_bounds__(256, 6) void k_attn6(const unsigned short* __restrict__ hB,
                                                  const unsigned short* __restrict__ hT,
                                                  const unsigned short* __restrict__ Ub,
                                                  const float* __restrict__ fw,
                                                  const float* __restrict__ fb,
                                                  const float* __restrict__ tgt,
                                                  float* __restrict__ out,
                                                  float* __restrict__ lossAcc) {
    __shared__ unsigned short sAB[32 * LCH];  // bf16 alpha [32 y][256 l], XOR-swizzled (16 KB)
    __shared__ float sRed[128];
    __shared__ float sInv[32];

    int b = blockIdx.x & 7;
    int y0 = (blockIdx.x >> 3) * 32;
    int tid = threadIdx.x;
    int w = tid >> 6, lane = tid & 63, lm = lane & 15, g = lane >> 4;

    const unsigned short* hBb = hB + (size_t)b * LPAD * FP;
    const unsigned short* hTb = hT + (size_t)b * FP * LPAD;
    char* sABc = (char*)sAB;

    short8 uf[2][2];
#pragma unroll
    for (int yt = 0; yt < 2; ++yt) {
        uf[yt][0] = *(const short8*)(Ub + (size_t)(y0 + yt * 16 + lm) * FP + g * 8);
        uf[yt][1] = *(const short8*)(Ub + (size_t)(y0 + yt * 16 + lm) * FP + 32 + g * 8);
    }

    // ---------------- pass 1: denominators ----------------
    float ssum[2] = {0.f, 0.f};
    for (int it = 0; it < 40; ++it) {
        int l0 = it * 64 + w * 16;
        const unsigned short* hrow = hBb + (size_t)l0 * FP;
        short8 a0 = *(const short8*)(hrow + lm * FP + g * 8);
        short8 a1 = *(const short8*)(hrow + lm * FP + 32 + g * 8);
#pragma unroll
        for (int yt = 0; yt < 2; ++yt) {
            f32x4 cc = {0.f, 0.f, 0.f, 0.f};
            cc = mfma_bf16(a0, uf[yt][0], cc);
            cc = mfma_bf16(a1, uf[yt][1], cc);
#pragma unroll
            for (int j = 0; j < 4; ++j)
                ssum[yt] += (l0 + g * 4 + j < LL) ? __expf(cc[j]) : 0.f;
        }
    }
#pragma unroll
    for (int yt = 0; yt < 2; ++yt) {
        float s = ssum[yt];
        s += __shfl_xor(s, 16);
        s += __shfl_xor(s, 32);
        if (g == 0) sRed[w * 32 + yt * 16 + lm] = s;
    }
    __syncthreads();
    if (tid < 32)
        sInv[tid] = 1.f / (sRed[tid] + sRed[32 + tid] + sRed[64 + tid] + sRed[96 + tid]);
    __syncthreads();

    // ---------------- pass 2 ----------------
    f32x4 macc[2][4];
#pragma unroll
    for (int yt = 0; yt < 2; ++yt)
#pragma unroll
        for (int ft = 0; ft < 4; ++ft) macc[yt][ft] = (f32x4){0.f, 0.f, 0.f, 0.f};

    float* alphaBase = out + 64001 + ((size_t)b * YY + y0) * LL;
    for (int c = 0; c < NCH; ++c) {
        // scores -> alpha bf16 into swizzled sAB (4 l-tiles per wave)
#pragma unroll
        for (int t = 0; t < 4; ++t) {
            int lt = w * 4 + t;
            int l0 = c * LCH + lt * 16;
            const unsigned short* hrow = hBb + (size_t)l0 * FP;
            short8 a0 = *(const short8*)(hrow + lm * FP + g * 8);
            short8 a1 = *(const short8*)(hrow + lm * FP + 32 + g * 8);
#pragma unroll
            for (int yt = 0; yt < 2; ++yt) {
                f32x4 cc = {0.f, 0.f, 0.f, 0.f};
                cc = mfma_bf16(a0, uf[yt][0], cc);
                cc = mfma_bf16(a1, uf[yt][1], cc);
                float inv = sInv[yt * 16 + lm];
                float av[4];
#pragma unroll
                for (int j = 0; j < 4; ++j)
                    av[j] = (l0 + g * 4 + j < LL) ? __expf(cc[j]) * inv : 0.f;
                int row = yt * 16 + lm;
                int off = row * 512 + ((lt * 32 + g * 8) ^ ((lm & 7) << 4));
                *(unsigned long long*)&sABc[off] = pack4bf(av);
            }
        }
        __syncthreads();   // sAB ready
        // m-MFMA: wave w handles k-chunks w*2, w*2+1; B-frags hoisted
#pragma unroll
        for (int i = 0; i < 2; ++i) {
            int kc = w * 2 + i;
            short8 bf[4];
#pragma unroll
            for (int ft = 0; ft < 4; ++ft)
                bf[ft] = *(const short8*)(hTb + (size_t)(ft * 16 + lm) * LPAD + c * LCH + kc * 32 + g * 8);
#pragma unroll
            for (int yt = 0; yt < 2; ++yt) {
                int row = yt * 16 + lm;
                short8 pa = *(const short8*)&sABc[row * 512 + ((kc * 64 + g * 16) ^ ((lm & 7) << 4))];
#pragma unroll
                for (int ft = 0; ft < 4; ++ft)
                    macc[yt][ft] = mfma_bf16(pa, bf[ft], macc[yt][ft]);
            }
        }
        // dump: wave per row -> one 1024-B contiguous store per row
#pragma unroll
        for (int rr = 0; rr < 8; ++rr) {
            int row = w * 8 + rr;
            int swz = (row & 7) << 4;
            int lc = lane * 4;
            if (c * LCH + lc < LL) {
                unsigned long long pv =
                    *(const unsigned long long*)&sABc[row * 512 + ((lane * 8) ^ swz)];
                f32x4 v = {bf2f((unsigned short)pv),
                           bf2f((unsigned short)(pv >> 16)),
                           bf2f((unsigned short)(pv >> 32)),
                           bf2f((unsigned short)(pv >> 48))};
                *(f32x4u*)(alphaBase + (size_t)row * LL + c * LCH + lc) = v;
            }
        }
        __syncthreads();   // all reads done before next chunk overwrites
    }

    // ---------------- epilogue: z partials (k-split) -> reduce -> BCE ----------------
#pragma unroll
    for (int yt = 0; yt < 2; ++yt) {
#pragma unroll
        for (int j = 0; j < 4; ++j) {
            int y = y0 + yt * 16 + g * 4 + j;
            float z = 0.f;
#pragma unroll
            for (int ft = 0; ft < 4; ++ft) {
                int f = ft * 16 + lm;
                float fwv = (f < FF) ? fw[(size_t)y * FF + f] : 0.f;
                z += macc[yt][ft][j] * fwv;
            }
            z += __shfl_xor(z, 1);
            z += __shfl_xor(z, 2);
            z += __shfl_xor(z, 4);
            z += __shfl_xor(z, 8);
            if (lm == 0) sRed[w * 32 + yt * 16 + g * 4 + j] = z;
        }
    }
    __syncthreads();
    if (w == 0) {
        float bce = 0.f;
        if (lane < 32) {
            int y = y0 + lane;
            float z = sRed[lane] + sRed[32 + lane] + sRed[64 + lane] + sRed[96 + lane] + fb[y];
            out[b * YY + y] = z;
            float tg = tgt[b * YY + y];
            bce = fmaxf(z, 0.f) - z * tg + log1pf(__expf(-fabsf(z)));
        }
        bce += __shfl_xor(bce, 1);
        bce += __shfl_xor(bce, 2);
        bce += __shfl_xor(bce, 4);
        bce += __shfl_xor(bce, 8);
        bce += __shfl_xor(bce, 16);
        bce += __shfl_xor(bce, 32);
        if (lane == 0) atomicAdd(lossAcc, bce);
    }
}

// ---- kernel C: finalize loss ----
__global__ void k_loss(const float* __restrict__ acc, float* __restrict__ out) {
    out[64000] = acc[0] / (float)(BB * YY);
}

extern "C" void kernel_launch(void* const* d_in, const int* in_sizes, int n_in,
                              void* d_out, int out_size, void* d_ws, size_t ws_size,
                              hipStream_t stream) {
    const int*   x    = (const int*)d_in[0];
    const float* tgt  = (const float*)d_in[1];
    const float* embW = (const float*)d_in[2];
    const float* cw   = (const float*)d_in[3];
    const float* cb   = (const float*)d_in[4];
    const float* Uw   = (const float*)d_in[5];
    const float* fw   = (const float*)d_in[6];
    const float* fb   = (const float*)d_in[7];
    float* out = (float*)d_out;

    float*          lossAcc = (float*)d_ws;
    unsigned short* wA = (unsigned short*)((char*)d_ws + 256);
    unsigned short* Ub = (unsigned short*)((char*)d_ws + 163840);
    unsigned short* hB = (unsigned short*)((char*)d_ws + 1212416);
    unsigned short* hT = (unsigned short*)((char*)d_ws + 3833856);

    hipMemsetAsync(d_ws, 0, 4, stream);
    k_prep<<<(YY * FP + 255) / 256, 256, 0, stream>>>(cw, wA, Uw, Ub);
    k_conv<<<BB * 40, 256, 0, stream>>>(x, embW, wA, cb, hB, hT);
    k_attn6<<<250 * 8, 256, 0, stream>>>(hB, hT, Ub, fw, fb, tgt, out, lossAcc);
    k_loss<<<1, 1, 0, stream>>>(lossAcc, out);
}

// Round 10
// 321.036 us; speedup vs baseline: 1.6214x; 1.6214x over previous
//
#include <hip/hip_runtime.h>
#include <hip/hip_bf16.h>
#include <math.h>

#define BB 8
#define LL 2500
#define LPAD 2560
#define DD 100
#define FF 50
#define FP 64
#define YY 8000
#define KS 9
#define LCH 512
#define NCH 5

typedef __attribute__((ext_vector_type(8))) short short8;
typedef __attribute__((ext_vector_type(4))) float f32x4;
typedef float f32x4u __attribute__((ext_vector_type(4), aligned(4)));

__device__ inline f32x4 mfma_bf16(short8 a, short8 b, f32x4 c) {
    return __builtin_amdgcn_mfma_f32_16x16x32_bf16(a, b, c, 0, 0, 0);
}

__device__ inline unsigned short f2bf(float x) {
    unsigned int u = __builtin_bit_cast(unsigned int, x);
    unsigned int r = u + 0x7fffu + ((u >> 16) & 1u);
    return (unsigned short)(r >> 16);
}

__device__ inline unsigned long long pack4bf(const float* a) {
    return (unsigned long long)f2bf(a[0])
         | ((unsigned long long)f2bf(a[1]) << 16)
         | ((unsigned long long)f2bf(a[2]) << 32)
         | ((unsigned long long)f2bf(a[3]) << 48);
}

__device__ inline float bf2f(unsigned short s) {
    return __builtin_bit_cast(float, (unsigned int)s << 16);
}

__device__ inline float tanhfast(float x) {
    float e = __expf(2.f * x);
    return 1.f - 2.f / (e + 1.f);
}

// ---- prep: weights -> wA[64][9][128] bf16; U_w -> Ub[Y][64] bf16 ----
__global__ void k_prep(const float* __restrict__ cw, unsigned short* __restrict__ wA,
                       const float* __restrict__ Uw, unsigned short* __restrict__ Ub) {
    int i = blockIdx.x * blockDim.x + threadIdx.x;
    if (i < 64 * KS * 128) {
        int f = i / (KS * 128);
        int r = i - f * (KS * 128);
        int kk = r >> 7;
        int d = r & 127;
        float v = (f < FF && d < DD) ? cw[(f * DD + d) * KS + kk] : 0.f;
        wA[i] = f2bf(v);
    }
    if (i < YY * FP) {
        int y = i >> 6, f = i & 63;
        float v = (f < FF) ? Uw[y * FF + f] : 0.f;
        Ub[i] = f2bf(v);
    }
}

// ---- kernel A: embed + conv1d(MFMA) + tanh -> hB[b][2560][64], hT[b][64][2560] bf16 ----
__global__ __launch_bounds__(256) void k_conv(const int* __restrict__ x,
                                              const float* __restrict__ embW,
                                              const unsigned short* __restrict__ wA,
                                              const float* __restrict__ cb,
                                              unsigned short* __restrict__ hB,
                                              unsigned short* __restrict__ hT) {
    __shared__ unsigned short eL[72 * 136];
    __shared__ int sX[72];
    int b = blockIdx.x & 7;
    int t = blockIdx.x >> 3;
    int l0 = t * 64;
    int tid = threadIdx.x;

    if (tid < 72) {
        int gl = l0 - 4 + tid;
        sX[tid] = (gl >= 0 && gl < LL) ? x[b * LL + gl] : -1;
    }
    __syncthreads();
    for (int i = tid; i < 72 * 25; i += 256) {
        int row = i / 25, c = i - row * 25;
        int id = sX[row];
        float4 v = make_float4(0.f, 0.f, 0.f, 0.f);
        if (id >= 0) v = *(const float4*)(embW + (size_t)id * DD + c * 4);
        float a[4] = {v.x, v.y, v.z, v.w};
        *(unsigned long long*)&eL[row * 136 + c * 4] = pack4bf(a);
    }
    for (int i = tid; i < 72 * 9; i += 256) {
        int row = i / 9, c = i - row * 9;
        *(unsigned long long*)&eL[row * 136 + 100 + c * 4] = 0ull;
    }
    __syncthreads();

    int w = tid >> 6, lane = tid & 63, lm = lane & 15, g = lane >> 4;
    f32x4 cacc[4];
#pragma unroll
    for (int mt = 0; mt < 4; ++mt) cacc[mt] = (f32x4){0.f, 0.f, 0.f, 0.f};

    for (int kk = 0; kk < KS; ++kk) {
#pragma unroll
        for (int dc = 0; dc < 4; ++dc) {
            short8 bfrag = *(const short8*)&eL[(w * 16 + lm + kk) * 136 + dc * 32 + g * 8];
#pragma unroll
            for (int mt = 0; mt < 4; ++mt) {
                short8 afrag = *(const short8*)(wA + ((mt * 16 + lm) * KS + kk) * 128 + dc * 32 + g * 8);
                cacc[mt] = mfma_bf16(afrag, bfrag, cacc[mt]);
            }
        }
    }

    int l = l0 + w * 16 + lm;
    unsigned long long packs[4];
#pragma unroll
    for (int mt = 0; mt < 4; ++mt) {
        float vals[4];
#pragma unroll
        for (int j = 0; j < 4; ++j) {
            int f = mt * 16 + g * 4 + j;
            vals[j] = (f < FF) ? tanhfast(cacc[mt][j] + cb[f]) : 0.f;
        }
        packs[mt] = pack4bf(vals);
        *(unsigned long long*)&hB[((size_t)b * LPAD + l) * FP + mt * 16 + g * 4] = packs[mt];
    }
    __syncthreads();
    unsigned short* hTile = eL;
#pragma unroll
    for (int mt = 0; mt < 4; ++mt)
#pragma unroll
        for (int j = 0; j < 4; ++j)
            hTile[(mt * 16 + g * 4 + j) * 72 + w * 16 + lm] =
                (unsigned short)(packs[mt] >> (16 * j));
    __syncthreads();
    {
        int f = tid >> 2, q = tid & 3;
        short8 v0 = *(const short8*)&hTile[f * 72 + q * 16];
        short8 v1 = *(const short8*)&hTile[f * 72 + q * 16 + 8];
        unsigned short* dst = hT + ((size_t)b * FP + f) * LPAD + l0 + q * 16;
        *(short8*)dst = v0;
        *(short8*)(dst + 8) = v1;
    }
}

// ---- kernel B: fused attention; block = (b, 32 y); 512-l chunks; NT wave-per-row dump ----
__global__ __launch_bounds__(256, 4) void k_attn5(const unsigned short* __restrict__ hB,
                                                  const unsigned short* __restrict__ hT,
                                                  const unsigned short* __restrict__ Ub,
                                                  const float* __restrict__ fw,
                                                  const float* __restrict__ fb,
                                                  const float* __restrict__ tgt,
                                                  float* __restrict__ out,
                                                  float* __restrict__ lossAcc) {
    __shared__ unsigned short sAB[32 * LCH];  // bf16 alpha [32 y][512 l], XOR-swizzled
    __shared__ float sRed[128];
    __shared__ float sInv[32];

    int b = blockIdx.x & 7;
    int y0 = (blockIdx.x >> 3) * 32;
    int tid = threadIdx.x;
    int w = tid >> 6, lane = tid & 63, lm = lane & 15, g = lane >> 4;

    const unsigned short* hBb = hB + (size_t)b * LPAD * FP;
    const unsigned short* hTb = hT + (size_t)b * FP * LPAD;
    char* sABc = (char*)sAB;

    short8 uf[2][2];
#pragma unroll
    for (int yt = 0; yt < 2; ++yt) {
        uf[yt][0] = *(const short8*)(Ub + (size_t)(y0 + yt * 16 + lm) * FP + g * 8);
        uf[yt][1] = *(const short8*)(Ub + (size_t)(y0 + yt * 16 + lm) * FP + 32 + g * 8);
    }

    // ---------------- pass 1: denominators ----------------
    float ssum[2] = {0.f, 0.f};
    for (int c = 0; c < NCH; ++c) {
#pragma unroll
        for (int t = 0; t < 8; ++t) {
            int l0 = c * LCH + (w * 8 + t) * 16;
            const unsigned short* hrow = hBb + (size_t)l0 * FP;
            short8 a0 = *(const short8*)(hrow + lm * FP + g * 8);
            short8 a1 = *(const short8*)(hrow + lm * FP + 32 + g * 8);
#pragma unroll
            for (int yt = 0; yt < 2; ++yt) {
                f32x4 cc = {0.f, 0.f, 0.f, 0.f};
                cc = mfma_bf16(a0, uf[yt][0], cc);
                cc = mfma_bf16(a1, uf[yt][1], cc);
#pragma unroll
                for (int j = 0; j < 4; ++j)
                    ssum[yt] += (l0 + g * 4 + j < LL) ? __expf(cc[j]) : 0.f;
            }
        }
    }
#pragma unroll
    for (int yt = 0; yt < 2; ++yt) {
        float s = ssum[yt];
        s += __shfl_xor(s, 16);
        s += __shfl_xor(s, 32);
        if (g == 0) sRed[w * 32 + yt * 16 + lm] = s;
    }
    __syncthreads();
    if (tid < 32)
        sInv[tid] = 1.f / (sRed[tid] + sRed[32 + tid] + sRed[64 + tid] + sRed[96 + tid]);
    __syncthreads();

    // ---------------- pass 2 ----------------
    f32x4 macc[2][4];
#pragma unroll
    for (int yt = 0; yt < 2; ++yt)
#pragma unroll
        for (int ft = 0; ft < 4; ++ft) macc[yt][ft] = (f32x4){0.f, 0.f, 0.f, 0.f};

    float* alphaBase = out + 64001 + ((size_t)b * YY + y0) * LL;
    for (int c = 0; c < NCH; ++c) {
        // scores -> alpha bf16 into swizzled sAB
#pragma unroll
        for (int t = 0; t < 8; ++t) {
            int lt = w * 8 + t;
            int l0 = c * LCH + lt * 16;
            const unsigned short* hrow = hBb + (size_t)l0 * FP;
            short8 a0 = *(const short8*)(hrow + lm * FP + g * 8);
            short8 a1 = *(const short8*)(hrow + lm * FP + 32 + g * 8);
#pragma unroll
            for (int yt = 0; yt < 2; ++yt) {
                f32x4 cc = {0.f, 0.f, 0.f, 0.f};
                cc = mfma_bf16(a0, uf[yt][0], cc);
                cc = mfma_bf16(a1, uf[yt][1], cc);
                float inv = sInv[yt * 16 + lm];
                float av[4];
#pragma unroll
                for (int j = 0; j < 4; ++j)
                    av[j] = (l0 + g * 4 + j < LL) ? __expf(cc[j]) * inv : 0.f;
                int row = yt * 16 + lm;
                int off = row * 1024 + ((lt * 32 + g * 8) ^ ((lm & 7) << 4));
                *(unsigned long long*)&sABc[off] = pack4bf(av);
            }
        }
        __syncthreads();   // sAB ready
        // m-MFMA: wave w handles k-chunks w*4..w*4+3; B-frags hoisted
#pragma unroll
        for (int i = 0; i < 4; ++i) {
            int kc = w * 4 + i;
            short8 bf[4];
#pragma unroll
            for (int ft = 0; ft < 4; ++ft)
                bf[ft] = *(const short8*)(hTb + (size_t)(ft * 16 + lm) * LPAD + c * LCH + kc * 32 + g * 8);
#pragma unroll
            for (int yt = 0; yt < 2; ++yt) {
                int row = yt * 16 + lm;
                short8 pa = *(const short8*)&sABc[row * 1024 + ((kc * 64 + g * 16) ^ ((lm & 7) << 4))];
#pragma unroll
                for (int ft = 0; ft < 4; ++ft)
                    macc[yt][ft] = mfma_bf16(pa, bf[ft], macc[yt][ft]);
            }
        }
        // dump: wave per row, 1024 B contiguous per instruction, NT (no L2 allocation)
#pragma unroll
        for (int rr = 0; rr < 8; ++rr) {
            int row = w * 8 + rr;
            float* rowp = alphaBase + (size_t)row * LL + c * LCH;
            int swz = (row & 7) << 4;
#pragma unroll
            for (int half = 0; half < 2; ++half) {
                int lc = half * 256 + lane * 4;
                if (c * LCH + lc < LL) {
                    unsigned long long pv =
                        *(const unsigned long long*)&sABc[row * 1024 + ((lc * 2) ^ swz)];
                    f32x4 v = {bf2f((unsigned short)pv),
                               bf2f((unsigned short)(pv >> 16)),
                               bf2f((unsigned short)(pv >> 32)),
                               bf2f((unsigned short)(pv >> 48))};
                    __builtin_nontemporal_store(v, (f32x4u*)(rowp + lc));
                }
            }
        }
        __syncthreads();   // all reads done before next chunk overwrites
    }

    // ---------------- epilogue: z partials (k-split) -> reduce -> BCE ----------------
#pragma unroll
    for (int yt = 0; yt < 2; ++yt) {
#pragma unroll
        for (int j = 0; j < 4; ++j) {
            int y = y0 + yt * 16 + g * 4 + j;
            float z = 0.f;
#pragma unroll
            for (int ft = 0; ft < 4; ++ft) {
                int f = ft * 16 + lm;
                float fwv = (f < FF) ? fw[(size_t)y * FF + f] : 0.f;
                z += macc[yt][ft][j] * fwv;
            }
            z += __shfl_xor(z, 1);
            z += __shfl_xor(z, 2);
            z += __shfl_xor(z, 4);
            z += __shfl_xor(z, 8);
            if (lm == 0) sRed[w * 32 + yt * 16 + g * 4 + j] = z;
        }
    }
    __syncthreads();
    if (w == 0) {
        float bce = 0.f;
        if (lane < 32) {
            int y = y0 + lane;
            float z = sRed[lane] + sRed[32 + lane] + sRed[64 + lane] + sRed[96 + lane] + fb[y];
            out[b * YY + y] = z;
            float tg = tgt[b * YY + y];
            bce = fmaxf(z, 0.f) - z * tg + log1pf(__expf(-fabsf(z)));
        }
        bce += __shfl_xor(bce, 1);
        bce += __shfl_xor(bce, 2);
        bce += __shfl_xor(bce, 4);
        bce += __shfl_xor(bce, 8);
        bce += __shfl_xor(bce, 16);
        bce += __shfl_xor(bce, 32);
        if (lane == 0) atomicAdd(lossAcc, bce);
    }
}

// ---- kernel C: finalize loss ----
__global__ void k_loss(const float* __restrict__ acc, float* __restrict__ out) {
    out[64000] = acc[0] / (float)(BB * YY);
}

extern "C" void kernel_launch(void* const* d_in, const int* in_sizes, int n_in,
                              void* d_out, int out_size, void* d_ws, size_t ws_size,
                              hipStream_t stream) {
    const int*   x    = (const int*)d_in[0];
    const float* tgt  = (const float*)d_in[1];
    const float* embW = (const float*)d_in[2];
    const float* cw   = (const float*)d_in[3];
    const float* cb   = (const float*)d_in[4];
    const float* Uw   = (const float*)d_in[5];
    const float* fw   = (const float*)d_in[6];
    const float* fb   = (const float*)d_in[7];
    float* out = (float*)d_out;

    float*          lossAcc = (float*)d_ws;
    unsigned short* wA = (unsigned short*)((char*)d_ws + 256);
    unsigned short* Ub = (unsigned short*)((char*)d_ws + 163840);
    unsigned short* hB = (unsigned short*)((char*)d_ws + 1212416);
    unsigned short* hT = (unsigned short*)((char*)d_ws + 3833856);

    hipMemsetAsync(d_ws, 0, 4, stream);
    k_prep<<<(YY * FP + 255) / 256, 256, 0, stream>>>(cw, wA, Uw, Ub);
    k_conv<<<BB * 40, 256, 0, stream>>>(x, embW, wA, cb, hB, hT);
    k_attn5<<<250 * 8, 256, 0, stream>>>(hB, hT, Ub, fw, fb, tgt, out, lossAcc);
    k_loss<<<1, 1, 0, stream>>>(lossAcc, out);
}

// Round 11
// 306.980 us; speedup vs baseline: 1.6957x; 1.0458x over previous
//
#include <hip/hip_runtime.h>
#include <hip/hip_bf16.h>
#include <math.h>

#define BB 8
#define LL 2500
#define LPAD 2560
#define DD 100
#define FF 50
#define FP 64
#define YY 8000
#define KS 9
#define LCH 256
#define NCH 10

typedef __attribute__((ext_vector_type(8))) short short8;
typedef __attribute__((ext_vector_type(4))) float f32x4;
typedef float f32x4u __attribute__((ext_vector_type(4), aligned(4)));

__device__ inline f32x4 mfma_bf16(short8 a, short8 b, f32x4 c) {
    return __builtin_amdgcn_mfma_f32_16x16x32_bf16(a, b, c, 0, 0, 0);
}

__device__ inline unsigned short f2bf(float x) {
    unsigned int u = __builtin_bit_cast(unsigned int, x);
    unsigned int r = u + 0x7fffu + ((u >> 16) & 1u);
    return (unsigned short)(r >> 16);
}

__device__ inline unsigned long long pack4bf(const float* a) {
    return (unsigned long long)f2bf(a[0])
         | ((unsigned long long)f2bf(a[1]) << 16)
         | ((unsigned long long)f2bf(a[2]) << 32)
         | ((unsigned long long)f2bf(a[3]) << 48);
}

__device__ inline float bf2f(unsigned short s) {
    return __builtin_bit_cast(float, (unsigned int)s << 16);
}

__device__ inline float tanhfast(float x) {
    float e = __expf(2.f * x);
    return 1.f - 2.f / (e + 1.f);
}

// ---- prep: weights -> wA[64][9][128] bf16; U_w -> Ub[Y][64] bf16 ----
__global__ void k_prep(const float* __restrict__ cw, unsigned short* __restrict__ wA,
                       const float* __restrict__ Uw, unsigned short* __restrict__ Ub) {
    int i = blockIdx.x * blockDim.x + threadIdx.x;
    if (i < 64 * KS * 128) {
        int f = i / (KS * 128);
        int r = i - f * (KS * 128);
        int kk = r >> 7;
        int d = r & 127;
        float v = (f < FF && d < DD) ? cw[(f * DD + d) * KS + kk] : 0.f;
        wA[i] = f2bf(v);
    }
    if (i < YY * FP) {
        int y = i >> 6, f = i & 63;
        float v = (f < FF) ? Uw[y * FF + f] : 0.f;
        Ub[i] = f2bf(v);
    }
}

// ---- kernel A: embed + conv1d(MFMA) + tanh -> hB[b][2560][64], hT[b][64][2560] bf16 ----
__global__ __launch_bounds__(256) void k_conv(const int* __restrict__ x,
                                              const float* __restrict__ embW,
                                              const unsigned short* __restrict__ wA,
                                              const float* __restrict__ cb,
                                              unsigned short* __restrict__ hB,
                                              unsigned short* __restrict__ hT) {
    __shared__ unsigned short eL[72 * 136];
    __shared__ int sX[72];
    int b = blockIdx.x & 7;
    int t = blockIdx.x >> 3;
    int l0 = t * 64;
    int tid = threadIdx.x;

    if (tid < 72) {
        int gl = l0 - 4 + tid;
        sX[tid] = (gl >= 0 && gl < LL) ? x[b * LL + gl] : -1;
    }
    __syncthreads();
    for (int i = tid; i < 72 * 25; i += 256) {
        int row = i / 25, c = i - row * 25;
        int id = sX[row];
        float4 v = make_float4(0.f, 0.f, 0.f, 0.f);
        if (id >= 0) v = *(const float4*)(embW + (size_t)id * DD + c * 4);
        float a[4] = {v.x, v.y, v.z, v.w};
        *(unsigned long long*)&eL[row * 136 + c * 4] = pack4bf(a);
    }
    for (int i = tid; i < 72 * 9; i += 256) {
        int row = i / 9, c = i - row * 9;
        *(unsigned long long*)&eL[row * 136 + 100 + c * 4] = 0ull;
    }
    __syncthreads();

    int w = tid >> 6, lane = tid & 63, lm = lane & 15, g = lane >> 4;
    f32x4 cacc[4];
#pragma unroll
    for (int mt = 0; mt < 4; ++mt) cacc[mt] = (f32x4){0.f, 0.f, 0.f, 0.f};

    for (int kk = 0; kk < KS; ++kk) {
#pragma unroll
        for (int dc = 0; dc < 4; ++dc) {
            short8 bfrag = *(const short8*)&eL[(w * 16 + lm + kk) * 136 + dc * 32 + g * 8];
#pragma unroll
            for (int mt = 0; mt < 4; ++mt) {
                short8 afrag = *(const short8*)(wA + ((mt * 16 + lm) * KS + kk) * 128 + dc * 32 + g * 8);
                cacc[mt] = mfma_bf16(afrag, bfrag, cacc[mt]);
            }
        }
    }

    int l = l0 + w * 16 + lm;
    unsigned long long packs[4];
#pragma unroll
    for (int mt = 0; mt < 4; ++mt) {
        float vals[4];
#pragma unroll
        for (int j = 0; j < 4; ++j) {
            int f = mt * 16 + g * 4 + j;
            vals[j] = (f < FF) ? tanhfast(cacc[mt][j] + cb[f]) : 0.f;
        }
        packs[mt] = pack4bf(vals);
        *(unsigned long long*)&hB[((size_t)b * LPAD + l) * FP + mt * 16 + g * 4] = packs[mt];
    }
    __syncthreads();
    unsigned short* hTile = eL;
#pragma unroll
    for (int mt = 0; mt < 4; ++mt)
#pragma unroll
        for (int j = 0; j < 4; ++j)
            hTile[(mt * 16 + g * 4 + j) * 72 + w * 16 + lm] =
                (unsigned short)(packs[mt] >> (16 * j));
    __syncthreads();
    {
        int f = tid >> 2, q = tid & 3;
        short8 v0 = *(const short8*)&hTile[f * 72 + q * 16];
        short8 v1 = *(const short8*)&hTile[f * 72 + q * 16 + 8];
        unsigned short* dst = hT + ((size_t)b * FP + f) * LPAD + l0 + q * 16;
        *(short8*)dst = v0;
        *(short8*)(dst + 8) = v1;
    }
}

// ---- kernel B: fused attention; dbuf sAB; 1 barrier/chunk; NT dump issued early ----
__global__ __launch_bounds__(256, 4) void k_attn7(const unsigned short* __restrict__ hB,
                                                  const unsigned short* __restrict__ hT,
                                                  const unsigned short* __restrict__ Ub,
                                                  const float* __restrict__ fw,
                                                  const float* __restrict__ fb,
                                                  const float* __restrict__ tgt,
                                                  float* __restrict__ out,
                                                  float* __restrict__ lossAcc) {
    __shared__ unsigned short sAB[2][32 * LCH];  // 2 x 16 KB, bf16 alpha, XOR-swizzled
    __shared__ float sRed[128];
    __shared__ float sInv[32];

    int b = blockIdx.x & 7;
    int y0 = (blockIdx.x >> 3) * 32;
    int tid = threadIdx.x;
    int w = tid >> 6, lane = tid & 63, lm = lane & 15, g = lane >> 4;

    const unsigned short* hBb = hB + (size_t)b * LPAD * FP;
    const unsigned short* hTb = hT + (size_t)b * FP * LPAD;

    short8 uf[2][2];
#pragma unroll
    for (int yt = 0; yt < 2; ++yt) {
        uf[yt][0] = *(const short8*)(Ub + (size_t)(y0 + yt * 16 + lm) * FP + g * 8);
        uf[yt][1] = *(const short8*)(Ub + (size_t)(y0 + yt * 16 + lm) * FP + 32 + g * 8);
    }

    // ---------------- pass 1: denominators (barrier-free) ----------------
    float ssum[2] = {0.f, 0.f};
    for (int it = 0; it < 40; ++it) {
        int l0 = it * 64 + w * 16;
        const unsigned short* hrow = hBb + (size_t)l0 * FP;
        short8 a0 = *(const short8*)(hrow + lm * FP + g * 8);
        short8 a1 = *(const short8*)(hrow + lm * FP + 32 + g * 8);
#pragma unroll
        for (int yt = 0; yt < 2; ++yt) {
            f32x4 cc = {0.f, 0.f, 0.f, 0.f};
            cc = mfma_bf16(a0, uf[yt][0], cc);
            cc = mfma_bf16(a1, uf[yt][1], cc);
#pragma unroll
            for (int j = 0; j < 4; ++j)
                ssum[yt] += (l0 + g * 4 + j < LL) ? __expf(cc[j]) : 0.f;
        }
    }
#pragma unroll
    for (int yt = 0; yt < 2; ++yt) {
        float s = ssum[yt];
        s += __shfl_xor(s, 16);
        s += __shfl_xor(s, 32);
        if (g == 0) sRed[w * 32 + yt * 16 + lm] = s;
    }
    __syncthreads();
    if (tid < 32)
        sInv[tid] = 1.f / (sRed[tid] + sRed[32 + tid] + sRed[64 + tid] + sRed[96 + tid]);
    __syncthreads();

    // ---------------- pass 2: 1 barrier per chunk, dbuf ----------------
    f32x4 macc[2][4];
#pragma unroll
    for (int yt = 0; yt < 2; ++yt)
#pragma unroll
        for (int ft = 0; ft < 4; ++ft) macc[yt][ft] = (f32x4){0.f, 0.f, 0.f, 0.f};

    float* alphaBase = out + 64001 + ((size_t)b * YY + y0) * LL;
    int buf = 0;
    for (int c = 0; c < NCH; ++c) {
        char* sw = (char*)sAB[buf];
        // phase S: scores -> alpha bf16 into swizzled sAB[buf]
#pragma unroll
        for (int t = 0; t < 4; ++t) {
            int lt = w * 4 + t;
            int l0 = c * LCH + lt * 16;
            const unsigned short* hrow = hBb + (size_t)l0 * FP;
            short8 a0 = *(const short8*)(hrow + lm * FP + g * 8);
            short8 a1 = *(const short8*)(hrow + lm * FP + 32 + g * 8);
#pragma unroll
            for (int yt = 0; yt < 2; ++yt) {
                f32x4 cc = {0.f, 0.f, 0.f, 0.f};
                cc = mfma_bf16(a0, uf[yt][0], cc);
                cc = mfma_bf16(a1, uf[yt][1], cc);
                float inv = sInv[yt * 16 + lm];
                float av[4];
#pragma unroll
                for (int j = 0; j < 4; ++j)
                    av[j] = (l0 + g * 4 + j < LL) ? __expf(cc[j]) * inv : 0.f;
                int row = yt * 16 + lm;
                int off = row * 512 + ((lt * 32 + g * 8) ^ ((lm & 7) << 4));
                *(unsigned long long*)&sw[off] = pack4bf(av);
            }
        }
        __syncthreads();   // single barrier: sAB[buf] ready; drains prev chunk's NT stores
        // phase D: dump FIRST (NT stores fly during m-MFMA + next scores)
#pragma unroll
        for (int rr = 0; rr < 8; ++rr) {
            int row = w * 8 + rr;
            int lc = lane * 4;
            if (c * LCH + lc < LL) {
                unsigned long long pv =
                    *(const unsigned long long*)&sw[row * 512 + ((lane * 8) ^ ((row & 7) << 4))];
                f32x4 v = {bf2f((unsigned short)pv),
                           bf2f((unsigned short)(pv >> 16)),
                           bf2f((unsigned short)(pv >> 32)),
                           bf2f((unsigned short)(pv >> 48))};
                __builtin_nontemporal_store(v,
                    (f32x4u*)(alphaBase + (size_t)row * LL + c * LCH + lc));
            }
        }
        // phase M: m-MFMA; wave w handles k-chunks w*2, w*2+1; B-frags hoisted
#pragma unroll
        for (int i = 0; i < 2; ++i) {
            int kc = w * 2 + i;
            short8 bf[4];
#pragma unroll
            for (int ft = 0; ft < 4; ++ft)
                bf[ft] = *(const short8*)(hTb + (size_t)(ft * 16 + lm) * LPAD + c * LCH + kc * 32 + g * 8);
#pragma unroll
            for (int yt = 0; yt < 2; ++yt) {
                int row = yt * 16 + lm;
                short8 pa = *(const short8*)&sw[row * 512 + ((kc * 64 + g * 16) ^ ((lm & 7) << 4))];
#pragma unroll
                for (int ft = 0; ft < 4; ++ft)
                    macc[yt][ft] = mfma_bf16(pa, bf[ft], macc[yt][ft]);
            }
        }
        buf ^= 1;
    }

    // ---------------- epilogue: z partials (k-split) -> reduce -> BCE ----------------
#pragma unroll
    for (int yt = 0; yt < 2; ++yt) {
#pragma unroll
        for (int j = 0; j < 4; ++j) {
            int y = y0 + yt * 16 + g * 4 + j;
            float z = 0.f;
#pragma unroll
            for (int ft = 0; ft < 4; ++ft) {
                int f = ft * 16 + lm;
                float fwv = (f < FF) ? fw[(size_t)y * FF + f] : 0.f;
                z += macc[yt][ft][j] * fwv;
            }
            z += __shfl_xor(z, 1);
            z += __shfl_xor(z, 2);
            z += __shfl_xor(z, 4);
            z += __shfl_xor(z, 8);
            if (lm == 0) sRed[w * 32 + yt * 16 + g * 4 + j] = z;
        }
    }
    __syncthreads();
    if (w == 0) {
        float bce = 0.f;
        if (lane < 32) {
            int y = y0 + lane;
            float z = sRed[lane] + sRed[32 + lane] + sRed[64 + lane] + sRed[96 + lane] + fb[y];
            out[b * YY + y] = z;
            float tg = tgt[b * YY + y];
            bce = fmaxf(z, 0.f) - z * tg + log1pf(__expf(-fabsf(z)));
        }
        bce += __shfl_xor(bce, 1);
        bce += __shfl_xor(bce, 2);
        bce += __shfl_xor(bce, 4);
        bce += __shfl_xor(bce, 8);
        bce += __shfl_xor(bce, 16);
        bce += __shfl_xor(bce, 32);
        if (lane == 0) atomicAdd(lossAcc, bce);
    }
}

// ---- kernel C: finalize loss ----
__global__ void k_loss(const float* __restrict__ acc, float* __restrict__ out) {
    out[64000] = acc[0] / (float)(BB * YY);
}

extern "C" void kernel_launch(void* const* d_in, const int* in_sizes, int n_in,
                              void* d_out, int out_size, void* d_ws, size_t ws_size,
                              hipStream_t stream) {
    const int*   x    = (const int*)d_in[0];
    const float* tgt  = (const float*)d_in[1];
    const float* embW = (const float*)d_in[2];
    const float* cw   = (const float*)d_in[3];
    const float* cb   = (const float*)d_in[4];
    const float* Uw   = (const float*)d_in[5];
    const float* fw   = (const float*)d_in[6];
    const float* fb   = (const float*)d_in[7];
    float* out = (float*)d_out;

    float*          lossAcc = (float*)d_ws;
    unsigned short* wA = (unsigned short*)((char*)d_ws + 256);
    unsigned short* Ub = (unsigned short*)((char*)d_ws + 163840);
    unsigned short* hB = (unsigned short*)((char*)d_ws + 1212416);
    unsigned short* hT = (unsigned short*)((char*)d_ws + 3833856);

    hipMemsetAsync(d_ws, 0, 4, stream);
    k_prep<<<(YY * FP + 255) / 256, 256, 0, stream>>>(cw, wA, Uw, Ub);
    k_conv<<<BB * 40, 256, 0, stream>>>(x, embW, wA, cb, hB, hT);
    k_attn7<<<250 * 8, 256, 0, stream>>>(hB, hT, Ub, fw, fb, tgt, out, lossAcc);
    k_loss<<<1, 1, 0, stream>>>(lossAcc, out);
}